// Round 14
// baseline (149.677 us; speedup 1.0000x reference)
//
#include <hip/hip_runtime.h>
#include <hip/hip_bf16.h>
#include <math.h>

// GNNAngle round 14: occupancy push on the R13 structure. R13 held 64 VGPR of
// raw float4 -> ~160 VGPR total -> 3 waves/SIMD (37%) -> the measured ~35%
// busy/occupancy everywhere. Fix: cvt each node's data to its f16x8 MFMA frag
// AS LOADS ARRIVE (4 VGPR/node vs 8), launch_bounds(256,5) (<=102 VGPR) ->
// 5 waves/SIMD = 62% occupancy. Everything else identical to R13.

#define NTHREADS 256    // 4 waves
#define CHUNK    32     // nodes per block
#define ASTRIDE  136    // f16 act row stride (b128 conflict-free in MLP)

typedef _Float16 f16;
typedef f16  f16x8 __attribute__((ext_vector_type(8)));
typedef f16  f16x4 __attribute__((ext_vector_type(4)));
typedef float f32x4 __attribute__((ext_vector_type(4)));

__device__ __forceinline__ float fast_tanh(float x) {
    float e = __expf(2.0f * x);
    return 1.0f - 2.0f * __builtin_amdgcn_rcpf(e + 1.0f);
}

__device__ __forceinline__ float fast_acos(float x) {
    // Abramowitz-Stegun 4.4.45: max abs error 6.7e-5 rad, branchless
    float ax = fabsf(x);
    float p = fmaf(-0.0187293f, ax, 0.0742610f);
    p = fmaf(p, ax, -0.2121144f);
    p = fmaf(p, ax, 1.5707288f);
    float r = sqrtf(1.0f - ax) * p;
    return (x >= 0.0f) ? r : (3.14159265358979f - r);
}

// ---- prep: W[i][j] (f32 [IN][128]) -> Wt[j][i] f16 [128][128], K zero-padded
__global__ void prep_weights(const float* __restrict__ W1,
                             const float* __restrict__ W2,
                             const float* __restrict__ W3,
                             f16* __restrict__ wt)
{
    int tid = blockIdx.x * 256 + threadIdx.x;
    if (tid >= 3 * 128 * 128) return;
    int layer = tid >> 14;
    int rem   = tid & 16383;
    int j     = rem >> 7;
    int i     = rem & 127;
    const float* W = (layer == 0) ? W1 : ((layer == 1) ? W2 : W3);
    int in_l = (layer == 0) ? 120 : 128;
    float v = (i < in_l) ? W[i * 128 + j] : 0.0f;
    wt[tid] = (f16)v;   // wt[layer][j][i]
}

// one MLP layer: dst[node][j] = tanh(sum_i src[node][i]*W[i][j] + b[j])
__device__ __forceinline__ void mlp_layer_mfma(const f16* __restrict__ wl,   // [128][128] f16 ([j][i])
                                               const float* __restrict__ bias,
                                               const f16* src, f16* dst,     // LDS, stride ASTRIDE
                                               int w, int lr, int lg)
{
    #pragma unroll
    for (int jj = 0; jj < 2; ++jj) {
        const int jt = w * 2 + jj;
        const f16* wr = wl + (jt * 16 + lr) * 128 + lg * 8;
        f16x8 a0 = *(const f16x8*)(wr);
        f16x8 a1 = *(const f16x8*)(wr + 32);
        f16x8 a2 = *(const f16x8*)(wr + 64);
        f16x8 a3 = *(const f16x8*)(wr + 96);
        f32x4 bv = *(const f32x4*)(bias + jt * 16 + lg * 4);
        #pragma unroll
        for (int nt = 0; nt < 2; ++nt) {
            const int node = nt * 16 + lr;
            const f16* sr = src + node * ASTRIDE + lg * 8;
            f16x8 bf0 = *(const f16x8*)(sr);
            f16x8 bf1 = *(const f16x8*)(sr + 32);
            f16x8 bf2 = *(const f16x8*)(sr + 64);
            f16x8 bf3 = *(const f16x8*)(sr + 96);
            f32x4 acc = {0.f, 0.f, 0.f, 0.f};
            acc = __builtin_amdgcn_mfma_f32_16x16x32_f16(a0, bf0, acc, 0, 0, 0);
            acc = __builtin_amdgcn_mfma_f32_16x16x32_f16(a1, bf1, acc, 0, 0, 0);
            acc = __builtin_amdgcn_mfma_f32_16x16x32_f16(a2, bf2, acc, 0, 0, 0);
            acc = __builtin_amdgcn_mfma_f32_16x16x32_f16(a3, bf3, acc, 0, 0, 0);
            f16x4 o;
            #pragma unroll
            for (int r = 0; r < 4; ++r)
                o[r] = (f16)fast_tanh(acc[r] + bv[r]);
            *(f16x4*)(dst + node * ASTRIDE + jt * 16 + lg * 4) = o;
        }
    }
}

__global__ __launch_bounds__(NTHREADS, 5)
void gnn_angle_fused(const float* __restrict__ edge_attr,
                     const f16*   __restrict__ wt,     // 3x[128][128] f16
                     const float* __restrict__ b1, const float* __restrict__ b2,
                     const float* __restrict__ b3,
                     const float* __restrict__ W4, const float* __restrict__ b4,
                     float* __restrict__ out, int n_nodes)
{
    __shared__ __attribute__((aligned(16))) f16   actA[CHUNK * ASTRIDE];
    __shared__ __attribute__((aligned(16))) f16   actB[CHUNK * ASTRIDE];
    __shared__ __attribute__((aligned(16))) float diag[4][8][16];   // rsq of Gram diag, 2 KB

    const int t = threadIdx.x;
    const int w = t >> 6;    // wave 0..3
    const int l = t & 63;
    const int base = blockIdx.x * CHUNK;
    const int lr = l & 15;
    const int lg = l >> 4;

    // K-pad feats 120..127 for all 32 rows, once
    actA[(t >> 3) * ASTRIDE + 120 + (t & 7)] = (f16)0.f;

    // wave w owns nodes m = 4c + w, c = 0..7; lane holds row lr, dims lg*8..+8
    const float* sw = edge_attr + ((long)base + w) * 512 + lr * 32 + lg * 8;

    // ---- load all 8 nodes; cvt to f16 frag AS EACH ARRIVES (4 VGPR/node) ----
    f16x8 f0, f1, f2, f3, f4, f5, f6, f7;
    #define CVT(fc, c)                                                         \
        {                                                                      \
            float4 da = make_float4(0.f,0.f,0.f,0.f), db = da;                 \
            if (full || (long)base + 4*(c) + w < n_nodes) {                    \
                da = *(const float4*)(sw + (c) * 2048);                        \
                db = *(const float4*)(sw + (c) * 2048 + 4);                    \
            }                                                                  \
            fc[0]=(f16)da.x; fc[1]=(f16)da.y; fc[2]=(f16)da.z; fc[3]=(f16)da.w;\
            fc[4]=(f16)db.x; fc[5]=(f16)db.y; fc[6]=(f16)db.z; fc[7]=(f16)db.w;\
        }
    {
        const bool full = (base + CHUNK <= n_nodes);
        CVT(f0,0) CVT(f1,1) CVT(f2,2) CVT(f3,3)
        CVT(f4,4) CVT(f5,5) CVT(f6,6) CVT(f7,7)
    }
    #undef CVT

    // ---- 8 independent Gram MFMAs ----
    f32x4 g0,g1,g2,g3,g4,g5,g6,g7;
    {
        f32x4 z = {0.f,0.f,0.f,0.f};
        g0 = __builtin_amdgcn_mfma_f32_16x16x32_f16(f0, f0, z, 0,0,0);
        g1 = __builtin_amdgcn_mfma_f32_16x16x32_f16(f1, f1, z, 0,0,0);
        g2 = __builtin_amdgcn_mfma_f32_16x16x32_f16(f2, f2, z, 0,0,0);
        g3 = __builtin_amdgcn_mfma_f32_16x16x32_f16(f3, f3, z, 0,0,0);
        g4 = __builtin_amdgcn_mfma_f32_16x16x32_f16(f4, f4, z, 0,0,0);
        g5 = __builtin_amdgcn_mfma_f32_16x16x32_f16(f5, f5, z, 0,0,0);
        g6 = __builtin_amdgcn_mfma_f32_16x16x32_f16(f6, f6, z, 0,0,0);
        g7 = __builtin_amdgcn_mfma_f32_16x16x32_f16(f7, f7, z, 0,0,0);
    }

    // ---- 16 diag lanes write rsq(G[ii]); ONE fence for all 8 nodes ----
    if (lg == (lr >> 2)) {
        const int r = lr & 3;
        diag[w][0][lr] = __builtin_amdgcn_rsqf(g0[r] + 1e-24f);
        diag[w][1][lr] = __builtin_amdgcn_rsqf(g1[r] + 1e-24f);
        diag[w][2][lr] = __builtin_amdgcn_rsqf(g2[r] + 1e-24f);
        diag[w][3][lr] = __builtin_amdgcn_rsqf(g3[r] + 1e-24f);
        diag[w][4][lr] = __builtin_amdgcn_rsqf(g4[r] + 1e-24f);
        diag[w][5][lr] = __builtin_amdgcn_rsqf(g5[r] + 1e-24f);
        diag[w][6][lr] = __builtin_amdgcn_rsqf(g6[r] + 1e-24f);
        diag[w][7][lr] = __builtin_amdgcn_rsqf(g7[r] + 1e-24f);
    }
    asm volatile("s_waitcnt lgkmcnt(0)" ::: "memory");
    __builtin_amdgcn_sched_barrier(0);

    // ---- normalize + acos + scatter (independent per node) ----
    #define FIN(gc, c)                                                     \
        {                                                                  \
            const float rc = diag[w][c][lr];                               \
            const f32x4 rr = *(const f32x4*)&diag[w][c][lg * 4];           \
            const int m = (c) * 4 + w;                                     \
            const int col = lr;                                            \
            _Pragma("unroll")                                              \
            for (int r2 = 0; r2 < 4; ++r2) {                               \
                const int row = lg * 4 + r2;                               \
                float cv = gc[r2] * rr[r2] * rc;                           \
                cv = fminf(fmaxf(cv, -1.0f + 1e-7f), 1.0f - 1e-7f);        \
                float ang = fast_acos(cv);                                 \
                if (row < col) {                                           \
                    const int p = 15*row - ((row*(row-1))>>1) + (col-row-1); \
                    actA[m * ASTRIDE + p] = (f16)ang;                      \
                }                                                          \
            }                                                              \
        }
    FIN(g0,0) FIN(g1,1) FIN(g2,2) FIN(g3,3)
    FIN(g4,4) FIN(g5,5) FIN(g6,6) FIN(g7,7)
    #undef FIN
    __syncthreads();

    // ---------------- Phase B: MLP on MFMA ----------------
    mlp_layer_mfma(wt,             b1, actA, actB, w, lr, lg);
    __syncthreads();
    mlp_layer_mfma(wt + 16384,     b2, actB, actA, w, lr, lg);
    __syncthreads();
    mlp_layer_mfma(wt + 2 * 16384, b3, actA, actB, w, lr, lg);
    __syncthreads();

    // ---------------- final 128->1 + sigmoid: 8 threads per node ----------------
    {
        const int node = t >> 3;       // 0..31
        const int part = t & 7;        // 0..7
        const int i0 = part * 16;
        const f16* sr = actB + node * ASTRIDE + i0;
        f16x8 h0 = *(const f16x8*)(sr);
        f16x8 h1 = *(const f16x8*)(sr + 8);
        float s = 0.f;
        #pragma unroll
        for (int e = 0; e < 8; ++e) s = fmaf((float)h0[e], W4[i0 + e], s);
        #pragma unroll
        for (int e = 0; e < 8; ++e) s = fmaf((float)h1[e], W4[i0 + 8 + e], s);
        s += __shfl_xor(s, 1);
        s += __shfl_xor(s, 2);
        s += __shfl_xor(s, 4);
        if (part == 0) {
            const long g = (long)base + node;
            if (g < n_nodes)
                out[g] = __builtin_amdgcn_rcpf(1.0f + __expf(-(s + b4[0])));
        }
    }
}

extern "C" void kernel_launch(void* const* d_in, const int* in_sizes, int n_in,
                              void* d_out, int out_size, void* d_ws, size_t ws_size,
                              hipStream_t stream) {
    // inputs: 0:x 1:edge_index 2:edge_attr 3:k 4:W1 5:b1 6:W2 7:b2 8:W3 9:b3 10:W4 11:b4
    const float* edge_attr = (const float*)d_in[2];
    const float* W1 = (const float*)d_in[4];
    const float* b1 = (const float*)d_in[5];
    const float* W2 = (const float*)d_in[6];
    const float* b2 = (const float*)d_in[7];
    const float* W3 = (const float*)d_in[8];
    const float* b3 = (const float*)d_in[9];
    const float* W4 = (const float*)d_in[10];
    const float* b4 = (const float*)d_in[11];
    float* out = (float*)d_out;
    f16* wt = (f16*)d_ws;                        // 3*128*128 f16 = 96 KB

    const int n_nodes = in_sizes[2] / 512;       // E*D / (16*32)

    prep_weights<<<(3 * 128 * 128 + 255) / 256, 256, 0, stream>>>(W1, W2, W3, wt);

    const int blocks = (n_nodes + CHUNK - 1) / CHUNK;
    gnn_angle_fused<<<blocks, NTHREADS, 0, stream>>>(
        edge_attr, wt, b1, b2, b3, W4, b4, out, n_nodes);
}